// Round 1
// baseline (95.257 us; speedup 1.0000x reference)
//
#include <hip/hip_runtime.h>
#include <hip/hip_bf16.h>

// GMP: y[n] = sum_{k,l} a[k,l] x[n-l] |x[n-l]|^k
//          + sum_{k,l,m} b[k,l,m] x[n-l] |x[n-l-m]|^k
//          + sum_{k,l,m} c[k,l,m] x[n-l] |x[n-l+m]|^k
// Ka=5,La=4; Kb=4,Lb=3,Mb=4; Kc=4,Lc=3,Mc=4; indices clipped to [0,N-1].
// out: [2,N] fp32 (re then im).

#define NTOT 1048576
#define BLOCK 256
#define EPT 4                       // elements per thread
#define TILE (BLOCK * EPT)          // 1024
#define HALO_L 5                    // max left reach: l+m = 2+3
#define HALO_R 3                    // max right reach: m-l = 3-0
#define WIN (TILE + HALO_L + HALO_R) // 1032

// pad every 32 floats by 1 -> stride-4 lane access becomes 2-way (free)
__device__ __forceinline__ int padidx(int j) { return j + (j >> 5); }
#define PWIN (WIN + (WIN >> 5) + 1)

__global__ void __launch_bounds__(BLOCK) gmp_kernel(
    const float* __restrict__ x_re, const float* __restrict__ x_im,
    const float* __restrict__ a_re, const float* __restrict__ a_im,
    const float* __restrict__ b_re, const float* __restrict__ b_im,
    const float* __restrict__ c_re, const float* __restrict__ c_im,
    float* __restrict__ out)
{
    __shared__ float s_xr[PWIN], s_xi[PWIN], s_r[PWIN];

    const int bs = blockIdx.x * TILE;

    // ---- stage tile + halo into LDS; |x| computed once per element ----
    for (int j = threadIdx.x; j < WIN; j += BLOCK) {
        int g = bs - HALO_L + j;
        g = max(g, 0);
        g = min(g, NTOT - 1);           // == jnp.clip semantics
        float xr = x_re[g];
        float xi = x_im[g];
        int p = padidx(j);
        s_xr[p] = xr;
        s_xi[p] = xi;
        s_r[p] = sqrtf(fmaf(xr, xr, xi * xi));
    }
    __syncthreads();

    // ---- per-thread register windows ----
    const int t0 = threadIdx.x * EPT;   // local tile offset of first element
    // r window: element e needs |x| at n-d, d in [-3,5] -> rw[e + 5 - d], idx 0..EPT+7
    float rw[EPT + 8];
#pragma unroll
    for (int i = 0; i < EPT + 8; ++i) rw[i] = s_r[padidx(t0 + i)];
    // x window: element e needs x at n-l, l in [0,3] -> xw[e + 3 - l], idx 0..EPT+2
    float xw_r[EPT + 3], xw_i[EPT + 3];
#pragma unroll
    for (int i = 0; i < EPT + 3; ++i) {
        int p = padidx(t0 + 2 + i);
        xw_r[i] = s_xr[p];
        xw_i[i] = s_xi[p];
    }

    float accr[EPT], acci[EPT];
#pragma unroll
    for (int e = 0; e < EPT; ++e) { accr[e] = 0.f; acci[e] = 0.f; }

#pragma unroll
    for (int l = 0; l < 4; ++l) {
        // merged deg-4 poly in r[n-l]: a[k,l] (+ b[k,l,0] + c[k,l,0] for l<3,k<4)
        float car[5], cai[5];
#pragma unroll
        for (int k = 0; k < 5; ++k) {
            car[k] = a_re[k * 4 + l];
            cai[k] = a_im[k * 4 + l];
        }
        if (l < 3) {
#pragma unroll
            for (int k = 0; k < 4; ++k) {
                car[k] += b_re[(k * 3 + l) * 4] + c_re[(k * 3 + l) * 4];
                cai[k] += b_im[(k * 3 + l) * 4] + c_im[(k * 3 + l) * 4];
            }
        }

        float Sr[EPT], Si[EPT];
#pragma unroll
        for (int e = 0; e < EPT; ++e) {
            float rv = rw[e + 5 - l];
            float sr = car[4], si = cai[4];
#pragma unroll
            for (int k = 3; k >= 0; --k) {
                sr = fmaf(sr, rv, car[k]);
                si = fmaf(si, rv, cai[k]);
            }
            Sr[e] = sr;
            Si[e] = si;
        }

        if (l < 3) {
#pragma unroll
            for (int m = 1; m < 4; ++m) {
                float br[4], bi[4], crr[4], cri[4];
#pragma unroll
                for (int k = 0; k < 4; ++k) {
                    br[k]  = b_re[(k * 3 + l) * 4 + m];
                    bi[k]  = b_im[(k * 3 + l) * 4 + m];
                    crr[k] = c_re[(k * 3 + l) * 4 + m];
                    cri[k] = c_im[(k * 3 + l) * 4 + m];
                }
#pragma unroll
                for (int e = 0; e < EPT; ++e) {
                    float rb = rw[e + 5 - l - m];   // |x[n-l-m]|
                    float sr = br[3], si = bi[3];
                    sr = fmaf(sr, rb, br[2]); si = fmaf(si, rb, bi[2]);
                    sr = fmaf(sr, rb, br[1]); si = fmaf(si, rb, bi[1]);
                    sr = fmaf(sr, rb, br[0]); si = fmaf(si, rb, bi[0]);
                    Sr[e] += sr; Si[e] += si;
                    float rc = rw[e + 5 - l + m];   // |x[n-l+m]|
                    float tr = crr[3], ti = cri[3];
                    tr = fmaf(tr, rc, crr[2]); ti = fmaf(ti, rc, cri[2]);
                    tr = fmaf(tr, rc, crr[1]); ti = fmaf(ti, rc, cri[1]);
                    tr = fmaf(tr, rc, crr[0]); ti = fmaf(ti, rc, cri[0]);
                    Sr[e] += tr; Si[e] += ti;
                }
            }
        }

        // acc += x[n-l] * S   (complex)
#pragma unroll
        for (int e = 0; e < EPT; ++e) {
            float xrv = xw_r[e + 3 - l], xiv = xw_i[e + 3 - l];
            accr[e] = fmaf(xrv, Sr[e], fmaf(-xiv, Si[e], accr[e]));
            acci[e] = fmaf(xrv, Si[e], fmaf(xiv, Sr[e], acci[e]));
        }
    }

    // ---- coalesced float4 stores: out[0..N) = re, out[N..2N) = im ----
    const int n0 = bs + t0;             // multiple of 4 -> 16B aligned
    float4 vre = make_float4(accr[0], accr[1], accr[2], accr[3]);
    float4 vim = make_float4(acci[0], acci[1], acci[2], acci[3]);
    *reinterpret_cast<float4*>(out + n0) = vre;
    *reinterpret_cast<float4*>(out + NTOT + n0) = vim;
}

extern "C" void kernel_launch(void* const* d_in, const int* in_sizes, int n_in,
                              void* d_out, int out_size, void* d_ws, size_t ws_size,
                              hipStream_t stream)
{
    const float* x_re = (const float*)d_in[0];
    const float* x_im = (const float*)d_in[1];
    const float* a_re = (const float*)d_in[2];
    const float* a_im = (const float*)d_in[3];
    const float* b_re = (const float*)d_in[4];
    const float* b_im = (const float*)d_in[5];
    const float* c_re = (const float*)d_in[6];
    const float* c_im = (const float*)d_in[7];
    float* out = (float*)d_out;

    dim3 grid(NTOT / TILE);   // 1024 blocks, no tail
    gmp_kernel<<<grid, BLOCK, 0, stream>>>(x_re, x_im, a_re, a_im,
                                           b_re, b_im, c_re, c_im, out);
}